// Round 1
// baseline (66.059 us; speedup 1.0000x reference)
//
#include <hip/hip_runtime.h>

#define P_NUM 40
#define N_VERT 128
#define H 256
#define W 256
#define BS 8
#define C_IN 64
#define PIX (H * W)
#define PIX4 (PIX / 4)

// Kernel A: even-odd point-in-polygon rasterization.
// One block per (polygon p, scanline y); 256 threads = one pixel column each.
// Phase 1: threads 0..127 test their edge for scanline crossing; crossing
// edges push xint into an LDS list (order-independent: parity = count mod 2).
// Phase 2: every thread counts strict (px < xint) over the list -> parity.
__global__ __launch_bounds__(256) void pnp_mask_kernel(
    const float* __restrict__ contour, float* __restrict__ maskws) {
    const int p = blockIdx.x;
    const int y = blockIdx.y;
    const int tid = threadIdx.x;

    __shared__ float sx[N_VERT];
    __shared__ float sy[N_VERT];
    __shared__ float xints[N_VERT];
    __shared__ int kcnt;

    if (tid < N_VERT) {
        // contour layout [P, N, 2]; (x,y) pairs are 8B-aligned
        const float2 v = reinterpret_cast<const float2*>(contour)[p * N_VERT + tid];
        sx[tid] = v.x;
        sy[tid] = v.y;
    }
    if (tid == 0) kcnt = 0;
    __syncthreads();

    const float py = (float)y;
    if (tid < N_VERT) {
        const float y1 = sy[tid];
        const int e2 = (tid + 1) & (N_VERT - 1);
        const float y2 = sy[e2];
        // crosses = (y1 > py) != (y2 > py)   -- exactly as reference
        const bool crosses = (y1 > py) != (y2 > py);
        if (crosses) {
            const float x1 = sx[tid];
            const float x2 = sx[e2];
            const float denom = (y2 == y1) ? 1.0f : (y2 - y1);
            // mul -> div -> add: no FMA contraction possible; IEEE f32 ==
            // XLA's result bit-for-bit.
            const float xint = (x2 - x1) * (py - y1) / denom + x1;
            const int slot = atomicAdd(&kcnt, 1);
            xints[slot] = xint;
        }
    }
    __syncthreads();

    const int K = kcnt;
    const float px = (float)tid;
    int cnt = 0;
    for (int k = 0; k < K; ++k) {
        cnt += (px < xints[k]) ? 1 : 0;  // broadcast LDS read, conflict-free
    }
    maskws[(p * H + y) * W + tid] = (float)(cnt & 1);
}

// Kernel B: gather masks into mask_batch (with the reference's faithful
// starts[i] = ct_num[i-1] indexing), running channel-max, then fused
// relu(max_mask * feat + feat) over all 64 feature channels.
// One thread per 4 consecutive pixels (float4 path throughout).
__global__ __launch_bounds__(256) void gather_fuse_kernel(
    const float* __restrict__ maskws, const float* __restrict__ feat,
    const int* __restrict__ ct_num, float* __restrict__ out_mask,
    float* __restrict__ out_cnn, int C) {
    const int gid = blockIdx.x * blockDim.x + threadIdx.x;  // BS * PIX4 threads
    const int i = gid / PIX4;
    const int q = gid - i * PIX4;

    const int cn = ct_num[i];
    const int start = (i == 0) ? 0 : ct_num[i - 1];  // faithful: NOT a cumsum

    float4 mx = make_float4(0.f, 0.f, 0.f, 0.f);
    for (int j = 0; j < C; ++j) {
        float4 m = make_float4(0.f, 0.f, 0.f, 0.f);
        if (j < cn) {
            int p = start + j;
            p = min(max(p, 0), P_NUM - 1);  // jnp.clip(idx, 0, P-1)
            m = reinterpret_cast<const float4*>(maskws)[p * PIX4 + q];
        }
        reinterpret_cast<float4*>(out_mask)[(size_t)(i * C + j) * PIX4 + q] = m;
        mx.x = fmaxf(mx.x, m.x);
        mx.y = fmaxf(mx.y, m.y);
        mx.z = fmaxf(mx.z, m.z);
        mx.w = fmaxf(mx.w, m.w);
    }

    for (int c = 0; c < C_IN; ++c) {
        const float4 f =
            reinterpret_cast<const float4*>(feat)[(size_t)(i * C_IN + c) * PIX4 + q];
        float4 r;
        // m in {0,1} exactly -> m*f+f == f or 2f exactly, FMA-insensitive.
        r.x = fmaxf(mx.x * f.x + f.x, 0.0f);
        r.y = fmaxf(mx.y * f.y + f.y, 0.0f);
        r.z = fmaxf(mx.z * f.z + f.z, 0.0f);
        r.w = fmaxf(mx.w * f.w + f.w, 0.0f);
        reinterpret_cast<float4*>(out_cnn)[(size_t)(i * C_IN + c) * PIX4 + q] = r;
    }
}

extern "C" void kernel_launch(void* const* d_in, const int* in_sizes, int n_in,
                              void* d_out, int out_size, void* d_ws, size_t ws_size,
                              hipStream_t stream) {
    const float* contour = (const float*)d_in[0];  // [P, N, 2] f32
    const float* feat = (const float*)d_in[1];     // [BS, C_IN, H, W] f32
    const int* ct_num = (const int*)d_in[2];       // [BS] i32

    float* out = (float*)d_out;
    // out = mask_batch [BS, C, H, W] ++ cnn_out [BS, C_IN, H, W]
    const int cnn_elems = BS * C_IN * PIX;
    const int C = (out_size - cnn_elems) / (BS * PIX);  // = max(ct_num)

    float* maskws = (float*)d_ws;  // [P, H, W] f32 = 10.5 MB
    float* out_mask = out;
    float* out_cnn = out + (size_t)BS * C * PIX;

    hipLaunchKernelGGL(pnp_mask_kernel, dim3(P_NUM, H), dim3(256), 0, stream,
                       contour, maskws);

    const int total = BS * PIX4;  // 131072 threads
    hipLaunchKernelGGL(gather_fuse_kernel, dim3(total / 256), dim3(256), 0, stream,
                       maskws, feat, ct_num, out_mask, out_cnn, C);
}

// Round 3
// 62.028 us; speedup vs baseline: 1.0650x; 1.0650x over previous
//
#include <hip/hip_runtime.h>

#define P_NUM 40
#define N_VERT 128
#define H 256
#define W 256
#define BS 8
#define C_IN 64
#define PIX (H * W)
#define PIX2 (PIX / 2)
#define PIX4 (PIX / 4)

// clang native vector types (accepted by __builtin_nontemporal_store,
// unlike HIP's float2/float4 structs)
typedef float vf2 __attribute__((ext_vector_type(2)));
typedef float vf4 __attribute__((ext_vector_type(4)));

// Kernel A: even-odd point-in-polygon rasterization.
// One block per (polygon p, scanline y); 256 threads = one pixel column each.
__global__ __launch_bounds__(256) void pnp_mask_kernel(
    const float* __restrict__ contour, float* __restrict__ maskws) {
    const int p = blockIdx.x;
    const int y = blockIdx.y;
    const int tid = threadIdx.x;

    __shared__ float sx[N_VERT];
    __shared__ float sy[N_VERT];
    __shared__ float xints[N_VERT];
    __shared__ int kcnt;

    if (tid < N_VERT) {
        const vf2 v = reinterpret_cast<const vf2*>(contour)[p * N_VERT + tid];
        sx[tid] = v.x;
        sy[tid] = v.y;
    }
    if (tid == 0) kcnt = 0;
    __syncthreads();

    const float py = (float)y;
    if (tid < N_VERT) {
        const float y1 = sy[tid];
        const int e2 = (tid + 1) & (N_VERT - 1);
        const float y2 = sy[e2];
        const bool crosses = (y1 > py) != (y2 > py);  // exactly as reference
        if (crosses) {
            const float x1 = sx[tid];
            const float x2 = sx[e2];
            const float denom = (y2 == y1) ? 1.0f : (y2 - y1);
            // mul -> div -> add: no FMA contraction; IEEE f32 == XLA bit-for-bit.
            const float xint = (x2 - x1) * (py - y1) / denom + x1;
            const int slot = atomicAdd(&kcnt, 1);
            xints[slot] = xint;
        }
    }
    __syncthreads();

    const int K = kcnt;
    const float px = (float)tid;
    int cnt = 0;
    for (int k = 0; k < K; ++k) {
        cnt += (px < xints[k]) ? 1 : 0;  // broadcast LDS read, conflict-free
    }
    maskws[(p * H + y) * W + tid] = (float)(cnt & 1);
}

// Kernel B1: gather masks -> mask_batch (faithful starts[i]=ct_num[i-1]),
// and running channel-max -> max_mask (ws). Thread per (image, 2 pixels):
// 1024 blocks (4 WG/CU) vs the old 512 — double the latency-hiding waves.
__global__ __launch_bounds__(256) void gather_max_kernel(
    const float* __restrict__ maskws, const int* __restrict__ ct_num,
    float* __restrict__ out_mask, float* __restrict__ max_mask, int C) {
    const int gid = blockIdx.x * blockDim.x + threadIdx.x;  // BS * PIX2
    const int i = gid / PIX2;
    const int q = gid - i * PIX2;

    const int cn = ct_num[i];
    const int start = (i == 0) ? 0 : ct_num[i - 1];  // faithful: NOT a cumsum

    vf2 mx = {0.f, 0.f};
    for (int j = 0; j < C; ++j) {
        vf2 m = {0.f, 0.f};
        if (j < cn) {
            int p = min(max(start + j, 0), P_NUM - 1);  // jnp.clip
            m = reinterpret_cast<const vf2*>(maskws)[p * PIX2 + q];
        }
        // Output only the host reads again -> non-temporal, keep L3 for feat.
        __builtin_nontemporal_store(
            m, reinterpret_cast<vf2*>(out_mask) + (size_t)(i * C + j) * PIX2 + q);
        mx.x = fmaxf(mx.x, m.x);
        mx.y = fmaxf(mx.y, m.y);
    }
    // max_mask is re-read immediately by B2 -> normal (cached) store.
    reinterpret_cast<vf2*>(max_mask)[gid] = mx;
}

// Kernel B2: pure elementwise stream relu(mx*f + f). Thread per (i,c,4 pixels):
// 32768 blocks -> full occupancy. max_mask (2 MB) stays L2-resident.
__global__ __launch_bounds__(256) void fuse_relu_kernel(
    const float* __restrict__ feat, const float* __restrict__ max_mask,
    float* __restrict__ out_cnn) {
    const int gid = blockIdx.x * blockDim.x + threadIdx.x;  // BS*C_IN*PIX4
    const int ic = gid / PIX4;   // i*C_IN + c
    const int q = gid - ic * PIX4;
    const int i = ic >> 6;       // /C_IN

    const vf4 f = reinterpret_cast<const vf4*>(feat)[(size_t)ic * PIX4 + q];
    const vf4 mm = reinterpret_cast<const vf4*>(max_mask)[i * PIX4 + q];
    vf4 r;
    // m in {0,1} exactly -> m*f+f == f or 2f exactly, FMA-insensitive.
    r.x = fmaxf(mm.x * f.x + f.x, 0.0f);
    r.y = fmaxf(mm.y * f.y + f.y, 0.0f);
    r.z = fmaxf(mm.z * f.z + f.z, 0.0f);
    r.w = fmaxf(mm.w * f.w + f.w, 0.0f);
    __builtin_nontemporal_store(
        r, reinterpret_cast<vf4*>(out_cnn) + (size_t)ic * PIX4 + q);
}

extern "C" void kernel_launch(void* const* d_in, const int* in_sizes, int n_in,
                              void* d_out, int out_size, void* d_ws, size_t ws_size,
                              hipStream_t stream) {
    const float* contour = (const float*)d_in[0];  // [P, N, 2] f32
    const float* feat = (const float*)d_in[1];     // [BS, C_IN, H, W] f32
    const int* ct_num = (const int*)d_in[2];       // [BS] i32

    float* out = (float*)d_out;
    const int cnn_elems = BS * C_IN * PIX;
    const int C = (out_size - cnn_elems) / (BS * PIX);  // = max(ct_num)

    float* maskws = (float*)d_ws;                        // [P, H, W] = 10.5 MB
    float* max_mask = maskws + (size_t)P_NUM * PIX;      // [BS, H, W] = 2 MB
    float* out_mask = out;
    float* out_cnn = out + (size_t)BS * C * PIX;

    hipLaunchKernelGGL(pnp_mask_kernel, dim3(P_NUM, H), dim3(256), 0, stream,
                       contour, maskws);

    hipLaunchKernelGGL(gather_max_kernel, dim3(BS * PIX2 / 256), dim3(256), 0,
                       stream, maskws, ct_num, out_mask, max_mask, C);

    hipLaunchKernelGGL(fuse_relu_kernel, dim3(BS * C_IN * PIX4 / 256), dim3(256),
                       0, stream, feat, max_mask, out_cnn);
}